// Round 2
// baseline (335.067 us; speedup 1.0000x reference)
//
#include <hip/hip_runtime.h>
#include <hip/hip_bf16.h>

// HierarchicalRouter: x[16384,2048] fp32, group_gate_w[8,2048], expert_gate_w[64,2048]
// out = concat(valid_mask[16384,64] as 0/1 float, normalized_weights[16384,64] float)
//
// Phase A: fp32 register-tiled GEMM for all 72 logits/token (no fp32 MFMA on CDNA4;
//   bf16 MFMA is numerically unsafe here: mask thresholds prob>=0.125 and with 1M
//   samples the nearest prob to the boundary is ~1e-6 away, bf16 error ~1e-3 flips it).
//   Thread map row=tid&7 (gate octet), col=tid>>3 (token octet): every LDS fragment is
//   read by 8 lanes -> broadcast, <=2-way bank aliasing (free). Register prefetch of
//   tile k+1 during compute of tile k hides global latency. S=16 K-split -> 1024 blocks
//   = 4 blocks/CU = 16 waves/CU.
// Phase B: 1024 blocks x 256 threads; block reduces S partials for 16 tokens with
//   coalesced float4 loads, 16 threads do dual softmax + mask, cooperative coalesced
//   stores of both output planes.

#define N_TOKENS 16384
#define N_EMBD   2048
#define BK       16

__global__ __launch_bounds__(256, 4)
void routerA(const float* __restrict__ x, const float* __restrict__ gw,
             const float* __restrict__ ew, float* __restrict__ P,
             int S, int KC)
{
    __shared__ float xs[BK][256];  // [k][token]  16 KB
    __shared__ float es[BK][64];   // [k][expert]  4 KB
    __shared__ float gs[BK][8];    // [k][group]  0.5 KB

    const int tid = threadIdx.x;
    const int ks  = blockIdx.x % S;       // K-split index
    const int tb  = blockIdx.x / S;       // token block
    const int t0  = tb * 256;
    const int row = tid & 7;              // gate octet: experts row*8..+7, group gate row
    const int col = tid >> 3;             // token octet: tokens t0+col*8..+7

    float accE[8][8];
    float accG[8];
    #pragma unroll
    for (int i = 0; i < 8; ++i) {
        accG[i] = 0.f;
        #pragma unroll
        for (int j = 0; j < 8; ++j) accE[i][j] = 0.f;
    }

    const int k0    = ks * KC;
    const int niter = KC >> 4;            // KC / BK

    // staging pointers
    const float* xg = x + (size_t)(t0 + tid) * N_EMBD + k0;   // 16 floats/tile (token t0+tid)
    const int we = tid & 63, wj = tid >> 6;                   // expert row, k-quad
    const float* eg = ew + (size_t)we * N_EMBD + k0 + wj * 4; // 4 floats/tile
    const int gg = tid & 7, gj = (tid >> 3) & 3;              // tid<32 only
    const float* gp = gw + (size_t)gg * N_EMBD + k0 + gj * 4;

    // ---- preload tile 0 into registers ----
    float4 rx0 = *(const float4*)(xg + 0);
    float4 rx1 = *(const float4*)(xg + 4);
    float4 rx2 = *(const float4*)(xg + 8);
    float4 rx3 = *(const float4*)(xg + 12);
    float4 re  = *(const float4*)(eg);
    float4 rg;
    if (tid < 32) rg = *(const float4*)(gp);

    for (int it = 0; it < niter; ++it) {
        // ---- commit staged registers to LDS ----
        xs[ 0][tid] = rx0.x; xs[ 1][tid] = rx0.y; xs[ 2][tid] = rx0.z; xs[ 3][tid] = rx0.w;
        xs[ 4][tid] = rx1.x; xs[ 5][tid] = rx1.y; xs[ 6][tid] = rx1.z; xs[ 7][tid] = rx1.w;
        xs[ 8][tid] = rx2.x; xs[ 9][tid] = rx2.y; xs[10][tid] = rx2.z; xs[11][tid] = rx2.w;
        xs[12][tid] = rx3.x; xs[13][tid] = rx3.y; xs[14][tid] = rx3.z; xs[15][tid] = rx3.w;
        es[wj*4+0][we] = re.x; es[wj*4+1][we] = re.y;
        es[wj*4+2][we] = re.z; es[wj*4+3][we] = re.w;
        if (tid < 32) {
            gs[gj*4+0][gg] = rg.x; gs[gj*4+1][gg] = rg.y;
            gs[gj*4+2][gg] = rg.z; gs[gj*4+3][gg] = rg.w;
        }
        __syncthreads();

        // ---- prefetch tile it+1 (awaited only at next commit) ----
        if (it + 1 < niter) {
            const int kb = (it + 1) * BK;
            rx0 = *(const float4*)(xg + kb + 0);
            rx1 = *(const float4*)(xg + kb + 4);
            rx2 = *(const float4*)(xg + kb + 8);
            rx3 = *(const float4*)(xg + kb + 12);
            re  = *(const float4*)(eg + kb);
            if (tid < 32) rg = *(const float4*)(gp + kb);
        }

        // ---- compute ----
        #pragma unroll 4
        for (int kk = 0; kk < BK; ++kk) {
            float4 a = *(const float4*)&xs[kk][col * 8];
            float4 b = *(const float4*)&xs[kk][col * 8 + 4];
            float4 c = *(const float4*)&es[kk][row * 8];
            float4 d = *(const float4*)&es[kk][row * 8 + 4];
            float  g = gs[kk][row];
            float xv[8] = {a.x, a.y, a.z, a.w, b.x, b.y, b.z, b.w};
            float wv[8] = {c.x, c.y, c.z, c.w, d.x, d.y, d.z, d.w};
            #pragma unroll
            for (int i = 0; i < 8; ++i) {
                #pragma unroll
                for (int j = 0; j < 8; ++j)
                    accE[i][j] = fmaf(xv[i], wv[j], accE[i][j]);
                accG[i] = fmaf(xv[i], g, accG[i]);
            }
        }
        __syncthreads();
    }

    // ---- epilogue: partial logits P[ks][t][0..63]=experts, [64..71]=group ----
    #pragma unroll
    for (int i = 0; i < 8; ++i) {
        const int t = t0 + col * 8 + i;
        float* p = P + ((size_t)ks * N_TOKENS + t) * 72;
        *(float4*)(p + row * 8)     = make_float4(accE[i][0], accE[i][1], accE[i][2], accE[i][3]);
        *(float4*)(p + row * 8 + 4) = make_float4(accE[i][4], accE[i][5], accE[i][6], accE[i][7]);
        p[64 + row] = accG[i];
    }
}

// 16 tokens per block; 1024 blocks.
__global__ __launch_bounds__(256)
void routerB(const float* __restrict__ P, float* __restrict__ out, int S)
{
    __shared__ float L[16 * 72];    // reduced logits, flat
    __shared__ float Ms[16 * 64];   // mask
    __shared__ float Ws[16 * 64];   // selected weights (pre-normalization)
    __shared__ float invS[16];      // 1 / weight_sum per token

    const int tid = threadIdx.x;
    const int t0  = blockIdx.x * 16;

    // ---- coalesced reduction over S partials: 16*72 = 1152 floats = 288 float4 ----
    float4 acc0 = make_float4(0.f, 0.f, 0.f, 0.f);
    float4 acc1 = make_float4(0.f, 0.f, 0.f, 0.f);
    for (int s = 0; s < S; ++s) {
        const float4* base = (const float4*)(P + ((size_t)s * N_TOKENS + t0) * 72);
        float4 v = base[tid];
        acc0.x += v.x; acc0.y += v.y; acc0.z += v.z; acc0.w += v.w;
        if (tid < 32) {
            float4 w = base[256 + tid];
            acc1.x += w.x; acc1.y += w.y; acc1.z += w.z; acc1.w += w.w;
        }
    }
    *(float4*)&L[tid * 4] = acc0;
    if (tid < 32) *(float4*)&L[1024 + tid * 4] = acc1;
    __syncthreads();

    // ---- softmax + hierarchical mask: one thread per token ----
    if (tid < 16) {
        const float* l = &L[tid * 72];
        // group softmax over l[64..71]
        float gpb[8];
        float gmax = l[64];
        #pragma unroll
        for (int g = 1; g < 8; ++g) gmax = fmaxf(gmax, l[64 + g]);
        float gsum = 0.f;
        #pragma unroll
        for (int g = 0; g < 8; ++g) { gpb[g] = __expf(l[64 + g] - gmax); gsum += gpb[g]; }
        float ginv = 1.f / gsum;
        float wsum = 0.f;
        #pragma unroll
        for (int g = 0; g < 8; ++g) {
            float gp = gpb[g] * ginv;
            float emax = l[g * 8];
            #pragma unroll
            for (int j = 1; j < 8; ++j) emax = fmaxf(emax, l[g * 8 + j]);
            float ep[8]; float esum = 0.f;
            #pragma unroll
            for (int j = 0; j < 8; ++j) { ep[j] = __expf(l[g * 8 + j] - emax); esum += ep[j]; }
            float einv = 1.f / esum;
            const bool gm = gp >= 0.125f;
            #pragma unroll
            for (int j = 0; j < 8; ++j) {
                float pe = ep[j] * einv;
                bool v = gm && (pe >= 0.125f);
                float ww = v ? gp * pe : 0.f;
                Ms[tid * 64 + g * 8 + j] = v ? 1.f : 0.f;
                Ws[tid * 64 + g * 8 + j] = ww;
                wsum += ww;
            }
        }
        invS[tid] = 1.f / fmaxf(wsum, 1e-9f);
    }
    __syncthreads();

    // ---- cooperative coalesced stores: 1024 floats per plane ----
    float4 m = *(const float4*)&Ms[tid * 4];
    float4 w = *(const float4*)&Ws[tid * 4];
    const float inv = invS[tid >> 4];
    w.x *= inv; w.y *= inv; w.z *= inv; w.w *= inv;
    *(float4*)(out + (size_t)t0 * 64 + tid * 4) = m;
    *(float4*)(out + (size_t)N_TOKENS * 64 + (size_t)t0 * 64 + tid * 4) = w;
}

extern "C" void kernel_launch(void* const* d_in, const int* in_sizes, int n_in,
                              void* d_out, int out_size, void* d_ws, size_t ws_size,
                              hipStream_t stream) {
    const float* x  = (const float*)d_in[0];
    const float* gw = (const float*)d_in[1];
    const float* ew = (const float*)d_in[2];
    float* out = (float*)d_out;
    float* P   = (float*)d_ws;

    // K-split factor: prefer 16 (1024 blocks, 4 blocks/CU); shrink if workspace small.
    int S = 16;
    while (S > 1 && (size_t)S * N_TOKENS * 72 * sizeof(float) > ws_size) S >>= 1;
    const int KC = N_EMBD / S;

    routerA<<<dim3(64 * S), dim3(256), 0, stream>>>(x, gw, ew, P, S, KC);
    routerB<<<dim3(N_TOKENS / 16), dim3(256), 0, stream>>>(P, out, S);
}

// Round 3
// 228.050 us; speedup vs baseline: 1.4693x; 1.4693x over previous
//
#include <hip/hip_runtime.h>
#include <hip/hip_bf16.h>

// HierarchicalRouter: x[16384,2048] fp32, group_gate_w[8,2048], expert_gate_w[64,2048]
// out = concat(valid_mask[16384,64] as 0/1 float, normalized_weights[16384,64] float)
//
// Single fused kernel, no workspace (R2 showed the K-split P round-trip inflates to
// ~580 MB HBM traffic via partial-line RMW writes and dominates runtime).
//
// 256 blocks x 512 threads (8 waves), 1 block/CU. Block owns 64 tokens; wave w owns
// K-chunk [w*256, w*256+256). Per-wave PRIVATE LDS tiles -> K-loop has NO barriers
// (same-wave ds_write->ds_read ordering via lgkmcnt only). Per-lane register tile:
// 8 tokens x (8 experts + 1 group gate) = 72 acc; all LDS fragment reads are 8-way
// broadcast / <=2-way bank aliased (free, m136). Register prefetch of tile+1 hides
// HBM latency (tile compute ~2300 cyc > ~900 cyc miss latency).
// Epilogue: 3-round LDS tree reduce over waves, per-token dual softmax + hierarchical
// mask (fp32 throughout -- bf16 would risk mask flips at the prob>=1/8 thresholds),
// coalesced float4 stores of both planes.

#define NT 16384
#define NE 2048

__global__ __launch_bounds__(512, 2)
void router(const float* __restrict__ x, const float* __restrict__ gw,
            const float* __restrict__ ew, float* __restrict__ out)
{
    // LDS plan (floats):
    //   staging: xs = [0,8192) 8w x [16][64];  es = [8192,16384) 8w x [16][64];
    //            gs = [16384,17408) 8w x [16][8]
    //   reduce:  Cbuf r=0..3 at [r*4608, r*4608+4608)  (overlaps staging; used after barrier)
    //   outputs: M = [18432,22528)  W = [22528,26624)
    __shared__ __align__(16) float sm[26624];   // 104 KB

    const int tid = threadIdx.x;
    const int w   = tid >> 6;          // wave id = K-chunk
    const int l   = tid & 63;          // lane
    const int row = l & 7;             // gate octet (experts row*8..+7, group gate row)
    const int col = l >> 3;            // token octet (tokens col*8..+7)
    const int t0  = blockIdx.x * 64;

    float* xs = sm + w * 1024;         // [k][tok]
    float* es = sm + 8192 + w * 1024;  // [k][expert]
    float* gs = sm + 16384 + w * 128;  // [k][group]

    const int k0 = w * 256;            // this wave's K-chunk

    float accE[8][8];
    float accG[8];
    #pragma unroll
    for (int i = 0; i < 8; ++i) {
        accG[i] = 0.f;
        #pragma unroll
        for (int j = 0; j < 8; ++j) accE[i][j] = 0.f;
    }

    const float* xg = x  + (size_t)(t0 + l) * NE + k0;             // own token row
    const float* eg = ew + (size_t)l        * NE + k0;             // own expert row
    const float* gp = gw + (size_t)(l >> 2) * NE + k0 + (l & 3)*4; // lanes<32: grp l>>2, quad l&3

    // ---- preload tile 0 ----
    float4 rx0 = *(const float4*)(xg + 0),  rx1 = *(const float4*)(xg + 4);
    float4 rx2 = *(const float4*)(xg + 8),  rx3 = *(const float4*)(xg + 12);
    float4 re0 = *(const float4*)(eg + 0),  re1 = *(const float4*)(eg + 4);
    float4 re2 = *(const float4*)(eg + 8),  re3 = *(const float4*)(eg + 12);
    float4 rg;
    if (l < 32) rg = *(const float4*)(gp);

    for (int it = 0; it < 16; ++it) {
        // ---- commit prefetched tile to this wave's private LDS (no barrier!) ----
        xs[ 0*64+l]=rx0.x; xs[ 1*64+l]=rx0.y; xs[ 2*64+l]=rx0.z; xs[ 3*64+l]=rx0.w;
        xs[ 4*64+l]=rx1.x; xs[ 5*64+l]=rx1.y; xs[ 6*64+l]=rx1.z; xs[ 7*64+l]=rx1.w;
        xs[ 8*64+l]=rx2.x; xs[ 9*64+l]=rx2.y; xs[10*64+l]=rx2.z; xs[11*64+l]=rx2.w;
        xs[12*64+l]=rx3.x; xs[13*64+l]=rx3.y; xs[14*64+l]=rx3.z; xs[15*64+l]=rx3.w;
        es[ 0*64+l]=re0.x; es[ 1*64+l]=re0.y; es[ 2*64+l]=re0.z; es[ 3*64+l]=re0.w;
        es[ 4*64+l]=re1.x; es[ 5*64+l]=re1.y; es[ 6*64+l]=re1.z; es[ 7*64+l]=re1.w;
        es[ 8*64+l]=re2.x; es[ 9*64+l]=re2.y; es[10*64+l]=re2.z; es[11*64+l]=re2.w;
        es[12*64+l]=re3.x; es[13*64+l]=re3.y; es[14*64+l]=re3.z; es[15*64+l]=re3.w;
        if (l < 32) {
            const int g = l >> 2, q = l & 3;
            gs[(q*4+0)*8+g]=rg.x; gs[(q*4+1)*8+g]=rg.y;
            gs[(q*4+2)*8+g]=rg.z; gs[(q*4+3)*8+g]=rg.w;
        }

        // ---- prefetch tile it+1 ----
        if (it + 1 < 16) {
            const int kb = (it + 1) * 16;
            rx0 = *(const float4*)(xg + kb + 0);  rx1 = *(const float4*)(xg + kb + 4);
            rx2 = *(const float4*)(xg + kb + 8);  rx3 = *(const float4*)(xg + kb + 12);
            re0 = *(const float4*)(eg + kb + 0);  re1 = *(const float4*)(eg + kb + 4);
            re2 = *(const float4*)(eg + kb + 8);  re3 = *(const float4*)(eg + kb + 12);
            if (l < 32) rg = *(const float4*)(gp + kb);
        }

        // ---- compute 16 k-steps ----
        #pragma unroll 4
        for (int kk = 0; kk < 16; ++kk) {
            float4 a = *(const float4*)&xs[kk*64 + col*8];
            float4 b = *(const float4*)&xs[kk*64 + col*8 + 4];
            float4 c = *(const float4*)&es[kk*64 + row*8];
            float4 d = *(const float4*)&es[kk*64 + row*8 + 4];
            float  g = gs[kk*8 + row];
            float xv[8] = {a.x,a.y,a.z,a.w,b.x,b.y,b.z,b.w};
            float wv[8] = {c.x,c.y,c.z,c.w,d.x,d.y,d.z,d.w};
            #pragma unroll
            for (int i = 0; i < 8; ++i) {
                #pragma unroll
                for (int j = 0; j < 8; ++j)
                    accE[i][j] = fmaf(xv[i], wv[j], accE[i][j]);
                accG[i] = fmaf(xv[i], g, accG[i]);
            }
        }
    }

    // ---- tree-reduce the 8 wave partials: Cbuf[r][tok][72] ----
    __syncthreads();   // staging LDS dead from here; Cbuf overlays it

    #define WRITE_C(r) { float* C = sm + (r)*4608;                                   \
        _Pragma("unroll") for (int i = 0; i < 8; ++i) { const int t = col*8 + i;     \
            *(float4*)&C[t*72 + row*8]   = make_float4(accE[i][0],accE[i][1],accE[i][2],accE[i][3]); \
            *(float4*)&C[t*72 + row*8+4] = make_float4(accE[i][4],accE[i][5],accE[i][6],accE[i][7]); \
            C[t*72 + 64 + row] = accG[i]; } }
    #define ADD_C(r) { const float* C = sm + (r)*4608;                               \
        _Pragma("unroll") for (int i = 0; i < 8; ++i) { const int t = col*8 + i;     \
            float4 a_ = *(const float4*)&C[t*72 + row*8];                            \
            float4 b_ = *(const float4*)&C[t*72 + row*8+4];                          \
            accE[i][0]+=a_.x; accE[i][1]+=a_.y; accE[i][2]+=a_.z; accE[i][3]+=a_.w;  \
            accE[i][4]+=b_.x; accE[i][5]+=b_.y; accE[i][6]+=b_.z; accE[i][7]+=b_.w;  \
            accG[i] += C[t*72 + 64 + row]; } }

    if (w >= 4) WRITE_C(w - 4);
    __syncthreads();
    if (w < 4)  ADD_C(w);
    __syncthreads();
    if (w == 2 || w == 3) WRITE_C(w - 2);
    __syncthreads();
    if (w < 2)  ADD_C(w);
    __syncthreads();
    if (w == 1) WRITE_C(0);
    __syncthreads();
    if (w == 0) { ADD_C(0); WRITE_C(0); }   // final logits land in Cbuf[0]
    __syncthreads();

    // ---- per-token dual softmax + hierarchical mask (threads 0..63) ----
    if (tid < 64) {
        const float* lg = sm + tid * 72;       // Cbuf[0][tid][·]
        float* M = sm + 18432 + tid * 64;
        float* W = sm + 22528 + tid * 64;

        float gpb[8];
        float gmax = lg[64];
        #pragma unroll
        for (int g = 1; g < 8; ++g) gmax = fmaxf(gmax, lg[64 + g]);
        float gsum = 0.f;
        #pragma unroll
        for (int g = 0; g < 8; ++g) { gpb[g] = __expf(lg[64 + g] - gmax); gsum += gpb[g]; }
        const float ginv = 1.f / gsum;

        float sel[64];
        float wsum = 0.f;
        #pragma unroll
        for (int g = 0; g < 8; ++g) {
            const float gp_ = gpb[g] * ginv;
            float emax = lg[g * 8];
            #pragma unroll
            for (int j = 1; j < 8; ++j) emax = fmaxf(emax, lg[g * 8 + j]);
            float ep[8]; float esum = 0.f;
            #pragma unroll
            for (int j = 0; j < 8; ++j) { ep[j] = __expf(lg[g * 8 + j] - emax); esum += ep[j]; }
            const float einv = 1.f / esum;
            const bool gm = gp_ >= 0.125f;
            #pragma unroll
            for (int j = 0; j < 8; ++j) {
                const float pe = ep[j] * einv;
                const bool v = gm && (pe >= 0.125f);
                const float ww = v ? gp_ * pe : 0.f;
                M[g * 8 + j] = v ? 1.f : 0.f;
                sel[g * 8 + j] = ww;
                wsum += ww;
            }
        }
        const float inv = 1.f / fmaxf(wsum, 1e-9f);
        #pragma unroll
        for (int e = 0; e < 64; ++e) W[e] = sel[e] * inv;
    }
    __syncthreads();

    // ---- coalesced stores: each plane = 64 tok x 64 = 1024 float4 ----
    const float4* M4 = (const float4*)(sm + 18432);
    const float4* W4 = (const float4*)(sm + 22528);
    float4* o0 = (float4*)(out + (size_t)t0 * 64);
    float4* o1 = (float4*)(out + (size_t)NT * 64 + (size_t)t0 * 64);
    o0[tid]       = M4[tid];
    o0[tid + 512] = M4[tid + 512];
    o1[tid]       = W4[tid];
    o1[tid + 512] = W4[tid + 512];

    #undef WRITE_C
    #undef ADD_C
}

extern "C" void kernel_launch(void* const* d_in, const int* in_sizes, int n_in,
                              void* d_out, int out_size, void* d_ws, size_t ws_size,
                              hipStream_t stream) {
    const float* x  = (const float*)d_in[0];
    const float* gw = (const float*)d_in[1];
    const float* ew = (const float*)d_in[2];
    float* out = (float*)d_out;
    (void)d_ws; (void)ws_size;

    router<<<dim3(NT / 64), dim3(512), 0, stream>>>(x, gw, ew, out);
}

// Round 5
// 201.048 us; speedup vs baseline: 1.6666x; 1.1343x over previous
//
#include <hip/hip_runtime.h>
#include <hip/hip_bf16.h>

// HierarchicalRouter: x[16384,2048] fp32, group_gate_w[8,2048], expert_gate_w[64,2048]
// out = concat(valid_mask[16384,64] as 0/1 float, normalized_weights[16384,64] float)
//
// f16-MFMA path with exact split:  v = h + l/2048, h=fp16(v), l=fp16((v-h)*2048).
// logit = acc_hh + acc_cross/2048 (3 MFMA passes; error ~2^-24, below fp32 wobble).
// 256 blocks x 512 thr (8 waves, 1 block/CU), 64 tokens/block, 80 gate-rows
// (64 experts + 8 group + 8 zero-pad), K chunked x128, double-buffered LDS (155 KB).
// Fragments stored pre-swizzled in mfma_f32_16x16x32_f16 lane order
// (A[m=lane&15][k=(lane>>4)*8+j], m89/m120-verified); reads are ds_read_b128 at
// lane*16 (conflict-free). QS=272/PL=1088/FP=2208 strides de-align staging writes.
// Wave = (token-tile w&3, K-half w>>2); 15 MFMAs per K-step. Epilogue: LDS K-reduce,
// per-token dual softmax + hierarchical mask (proven R3 fp32 code), coalesced stores.
//
// R4 bug fixed here: stage_commit was called with the CHUNK index (0..15) instead of
// the double-buffer index (0/1), writing up to ~1.2 MB past the LDS allocation from
// chunk 1 onward -> garbage fragments -> absmax 1.0. Now stage_commit((c+1)&1).

#define NT 16384
#define NE 2048
#define KC 128
#define NCHUNK 16

#define QS    272
#define PL    1088
#define FP    2208
#define XB    44160
#define BUFSZ 79488
#define LDS_BYTES 158976

typedef _Float16 v8h __attribute__((ext_vector_type(8)));
typedef float    v4f __attribute__((ext_vector_type(4)));

__global__ __launch_bounds__(512, 2)
void router(const float* __restrict__ x, const float* __restrict__ gw,
            const float* __restrict__ ew, float* __restrict__ out)
{
    __shared__ __align__(16) char sm[LDS_BYTES];
    const int tid  = threadIdx.x;
    const int lane = tid & 63;
    const int w    = tid >> 6;
    const int t0   = blockIdx.x * 64;

    // ---- staging descriptors (wave-uniform: waves 0-3 have 3 W-slots, 4-7 have 2) ----
    const float* wsrc[3]; int who[3]; int wmode[3];   // 0 none, 1 zero-pad, 2 load
    #pragma unroll
    for (int i = 0; i < 3; ++i) {
        int s = tid + i * 512;
        if (s >= 1280) { wmode[i] = 0; wsrc[i] = ew; who[i] = 0; continue; }
        int gate = s >> 4, kslot = s & 15;
        int ks = kslot >> 2, q = kslot & 3;
        who[i] = ((gate >> 4) * 4 + ks) * FP + q * QS + (gate & 15) * 16;
        if (gate < 64)      { wmode[i] = 2; wsrc[i] = ew + (size_t)gate * NE + kslot * 8; }
        else if (gate < 72) { wmode[i] = 2; wsrc[i] = gw + (size_t)(gate - 64) * NE + kslot * 8; }
        else                { wmode[i] = 1; wsrc[i] = ew; }
    }
    const float* xsrc[2]; int xho[2];
    #pragma unroll
    for (int i = 0; i < 2; ++i) {
        int s = tid + i * 512;
        int token = s >> 4, kslot = s & 15;
        int ks = kslot >> 2, q = kslot & 3;
        xho[i] = XB + ((token >> 4) * 4 + ks) * FP + q * QS + (token & 15) * 16;
        xsrc[i] = x + (size_t)(t0 + token) * NE + kslot * 8;
    }

    float4 wr[3][2], xr[2][2];

    auto stage_load = [&](int c) {
        const int kc = c * KC;
        #pragma unroll
        for (int i = 0; i < 3; ++i) {
            if (wmode[i] == 2) {
                wr[i][0] = *(const float4*)(wsrc[i] + kc);
                wr[i][1] = *(const float4*)(wsrc[i] + kc + 4);
            } else {
                wr[i][0] = make_float4(0.f, 0.f, 0.f, 0.f);
                wr[i][1] = make_float4(0.f, 0.f, 0.f, 0.f);
            }
        }
        #pragma unroll
        for (int i = 0; i < 2; ++i) {
            xr[i][0] = *(const float4*)(xsrc[i] + kc);
            xr[i][1] = *(const float4*)(xsrc[i] + kc + 4);
        }
    };

    auto split8 = [](const float4& a, const float4& b, v8h& h, v8h& l) {
        float v[8] = {a.x, a.y, a.z, a.w, b.x, b.y, b.z, b.w};
        #pragma unroll
        for (int j = 0; j < 8; ++j) {
            _Float16 hh = (_Float16)v[j];
            h[j] = hh;
            l[j] = (_Float16)((v[j] - (float)hh) * 2048.0f);
        }
    };

    auto stage_commit = [&](int buf) {
        const int bb = buf * BUFSZ;   // buf MUST be 0 or 1
        #pragma unroll
        for (int i = 0; i < 3; ++i) {
            if (wmode[i] == 0) continue;
            v8h h, l;
            split8(wr[i][0], wr[i][1], h, l);
            *(v8h*)(sm + bb + who[i])      = h;
            *(v8h*)(sm + bb + who[i] + PL) = l;
        }
        #pragma unroll
        for (int i = 0; i < 2; ++i) {
            v8h h, l;
            split8(xr[i][0], xr[i][1], h, l);
            *(v8h*)(sm + bb + xho[i])      = h;
            *(v8h*)(sm + bb + xho[i] + PL) = l;
        }
    };

    const int tt = w & 3, s2 = w >> 2;
    v4f accHH[5], accC[5];
    #pragma unroll
    for (int g = 0; g < 5; ++g) { accHH[g] = (v4f)(0.f); accC[g] = (v4f)(0.f); }
    const int rdo = (lane >> 4) * QS + (lane & 15) * 16;

    // ---- pipeline: one barrier per chunk; loads for c+1 fly over barrier+compute ----
    stage_load(0);
    stage_commit(0);
    for (int c = 0; c < NCHUNK; ++c) {
        if (c + 1 < NCHUNK) stage_load(c + 1);
        __syncthreads();
        {   // compute chunk c from buf[c&1]
            const int bb = (c & 1) * BUFSZ;
            #pragma unroll
            for (int ksl = 0; ksl < 2; ++ksl) {
                const int ks = s2 * 2 + ksl;
                const char* xb = sm + bb + XB + (tt * 4 + ks) * FP + rdo;
                v8h Bh = *(const v8h*)xb;
                v8h Bl = *(const v8h*)(xb + PL);
                #pragma unroll
                for (int g = 0; g < 5; ++g) {
                    const char* wb = sm + bb + (g * 4 + ks) * FP + rdo;
                    v8h Ah = *(const v8h*)wb;
                    v8h Al = *(const v8h*)(wb + PL);
                    accHH[g] = __builtin_amdgcn_mfma_f32_16x16x32_f16(Ah, Bh, accHH[g], 0, 0, 0);
                    accC[g]  = __builtin_amdgcn_mfma_f32_16x16x32_f16(Ah, Bl, accC[g], 0, 0, 0);
                    accC[g]  = __builtin_amdgcn_mfma_f32_16x16x32_f16(Al, Bh, accC[g], 0, 0, 0);
                }
            }
        }
        if (c + 1 < NCHUNK) stage_commit((c + 1) & 1);   // <-- fixed: buffer index, not chunk
    }
    __syncthreads();

    // ---- K-reduce across the two wave halves ----
    float part[5][4];
    #pragma unroll
    for (int g = 0; g < 5; ++g)
        #pragma unroll
        for (int r = 0; r < 4; ++r)
            part[g][r] = accHH[g][r] + accC[g][r] * (1.0f / 2048.0f);

    float* red = (float*)sm;
    if (w >= 4) {
        #pragma unroll
        for (int g = 0; g < 5; ++g)
            #pragma unroll
            for (int r = 0; r < 4; ++r)
                red[((tt * 5 + g) * 4 + r) * 64 + lane] = part[g][r];
    }
    __syncthreads();
    float* la = (float*)(sm + 24576);   // [64 tokens][80 gates]
    if (w < 4) {
        #pragma unroll
        for (int g = 0; g < 5; ++g)
            #pragma unroll
            for (int r = 0; r < 4; ++r) {
                float v = part[g][r] + red[((tt * 5 + g) * 4 + r) * 64 + lane];
                int gate  = g * 16 + (lane >> 4) * 4 + r;   // D row = gate
                int token = tt * 16 + (lane & 15);          // D col = token
                la[token * 80 + gate] = v;
            }
    }
    __syncthreads();

    // ---- per-token dual softmax + hierarchical mask ----
    if (tid < 64) {
        const float* lg = la + tid * 80;              // [0..63]=experts, [64..71]=groups
        float* M = (float*)(sm + 45056) + tid * 64;
        float* W = (float*)(sm + 61440) + tid * 64;

        float gpb[8];
        float gmax = lg[64];
        #pragma unroll
        for (int g = 1; g < 8; ++g) gmax = fmaxf(gmax, lg[64 + g]);
        float gsum = 0.f;
        #pragma unroll
        for (int g = 0; g < 8; ++g) { gpb[g] = __expf(lg[64 + g] - gmax); gsum += gpb[g]; }
        const float ginv = 1.f / gsum;

        float sel[64];
        float wsum = 0.f;
        #pragma unroll
        for (int g = 0; g < 8; ++g) {
            const float gp_ = gpb[g] * ginv;
            float emax = lg[g * 8];
            #pragma unroll
            for (int j = 1; j < 8; ++j) emax = fmaxf(emax, lg[g * 8 + j]);
            float ep[8]; float esum = 0.f;
            #pragma unroll
            for (int j = 0; j < 8; ++j) { ep[j] = __expf(lg[g * 8 + j] - emax); esum += ep[j]; }
            const float einv = 1.f / esum;
            const bool gm = gp_ >= 0.125f;
            #pragma unroll
            for (int j = 0; j < 8; ++j) {
                const float pe = ep[j] * einv;
                const bool v = gm && (pe >= 0.125f);
                const float ww = v ? gp_ * pe : 0.f;
                M[g * 8 + j] = v ? 1.f : 0.f;
                sel[g * 8 + j] = ww;
                wsum += ww;
            }
        }
        const float inv = 1.f / fmaxf(wsum, 1e-9f);
        #pragma unroll
        for (int e = 0; e < 64; ++e) W[e] = sel[e] * inv;
    }
    __syncthreads();

    // ---- coalesced stores ----
    const float4* M4 = (const float4*)(sm + 45056);
    const float4* W4 = (const float4*)(sm + 61440);
    float4* o0 = (float4*)(out + (size_t)t0 * 64);
    float4* o1 = (float4*)(out + (size_t)NT * 64 + (size_t)t0 * 64);
    o0[tid]       = M4[tid];
    o0[tid + 512] = M4[tid + 512];
    o1[tid]       = W4[tid];
    o1[tid + 512] = W4[tid + 512];
}

extern "C" void kernel_launch(void* const* d_in, const int* in_sizes, int n_in,
                              void* d_out, int out_size, void* d_ws, size_t ws_size,
                              hipStream_t stream) {
    const float* x  = (const float*)d_in[0];
    const float* gw = (const float*)d_in[1];
    const float* ew = (const float*)d_in[2];
    float* out = (float*)d_out;
    (void)d_ws; (void)ws_size;

    router<<<dim3(NT / 64), dim3(512), 0, stream>>>(x, gw, ew, out);
}